// Round 1
// baseline (3207.471 us; speedup 1.0000x reference)
//
#include <hip/hip_runtime.h>
#include <cstddef>

// Problem constants
#define SQ   2048      // sequence length
#define DH   256       // per-head dim (= model dim of input/output)
#define NH   8         // heads
#define BATCH 4
#define MROWS (BATCH*SQ)       // 8192
#define HID  (NH*DH)           // 2048

// ===================== Kernel A: fused QKV projection =====================
// X:[8192,256] row-major. W{q,k,v}:[2048,256] row-major (torch Linear weight).
// Output layout (head-major for attention): ws[((b*8+h)*2048 + s)*256 + dd]
// 64x64 tile per block, 256 threads, each 4x4 outputs, K staged in LDS
// transposed ([kk][row], pad 68) so compute reads are ds_read_b128.
__global__ void __launch_bounds__(256) qkv_proj_kernel(
    const float* __restrict__ X,
    const float* __restrict__ Wq, const float* __restrict__ Wk, const float* __restrict__ Wv,
    const float* __restrict__ bq, const float* __restrict__ bk, const float* __restrict__ bv,
    float* __restrict__ q_ws, float* __restrict__ k_ws, float* __restrict__ v_ws)
{
    __shared__ float Xs[32*68];   // [kk][m-row]
    __shared__ float Wsh[32*68];  // [kk][n-row]
    const int tid = threadIdx.x;
    const int m0 = blockIdx.x * 64;
    const int ng = blockIdx.y * 64;         // 0..6143, 64-aligned
    const int which = ng >> 11;             // 0=q,1=k,2=v
    const int n0 = ng & 2047;
    const float* __restrict__ W    = (which == 0) ? Wq : (which == 1) ? Wk : Wv;
    const float* __restrict__ bias = (which == 0) ? bq : (which == 1) ? bk : bv;
    float* __restrict__ outp       = (which == 0) ? q_ws : (which == 1) ? k_ws : v_ws;

    const int lrow = tid >> 2;          // 0..63 staging row
    const int lk0  = (tid & 3) * 8;     // 0..24 staging k-offset
    const int tx = tid & 15, ty = tid >> 4;

    float acc[4][4] = {};   // [i=m-sub][j=n-sub]

    for (int kc = 0; kc < 256; kc += 32) {
        float4 xa = *(const float4*)&X[(size_t)(m0 + lrow) * 256 + kc + lk0];
        float4 xb = *(const float4*)&X[(size_t)(m0 + lrow) * 256 + kc + lk0 + 4];
        float4 wa = *(const float4*)&W[(size_t)(n0 + lrow) * 256 + kc + lk0];
        float4 wb = *(const float4*)&W[(size_t)(n0 + lrow) * 256 + kc + lk0 + 4];
        __syncthreads();   // previous chunk fully consumed
        Xs[(lk0+0)*68 + lrow] = xa.x;  Xs[(lk0+1)*68 + lrow] = xa.y;
        Xs[(lk0+2)*68 + lrow] = xa.z;  Xs[(lk0+3)*68 + lrow] = xa.w;
        Xs[(lk0+4)*68 + lrow] = xb.x;  Xs[(lk0+5)*68 + lrow] = xb.y;
        Xs[(lk0+6)*68 + lrow] = xb.z;  Xs[(lk0+7)*68 + lrow] = xb.w;
        Wsh[(lk0+0)*68 + lrow] = wa.x; Wsh[(lk0+1)*68 + lrow] = wa.y;
        Wsh[(lk0+2)*68 + lrow] = wa.z; Wsh[(lk0+3)*68 + lrow] = wa.w;
        Wsh[(lk0+4)*68 + lrow] = wb.x; Wsh[(lk0+5)*68 + lrow] = wb.y;
        Wsh[(lk0+6)*68 + lrow] = wb.z; Wsh[(lk0+7)*68 + lrow] = wb.w;
        __syncthreads();
        #pragma unroll 8
        for (int kk = 0; kk < 32; ++kk) {
            float4 a4 = *(float4*)&Xs[kk*68 + ty*4];
            float4 b4 = *(float4*)&Wsh[kk*68 + tx*4];
            float a[4] = {a4.x, a4.y, a4.z, a4.w};
            float b[4] = {b4.x, b4.y, b4.z, b4.w};
            #pragma unroll
            for (int i = 0; i < 4; ++i)
                #pragma unroll
                for (int j = 0; j < 4; ++j)
                    acc[i][j] += a[i] * b[j];
        }
    }

    // write out: head-major layout, float4 per (i)
    const int ncol0 = n0 + tx*4;
    float4 bv4 = *(const float4*)&bias[ncol0];
    const int h  = ncol0 >> 8;      // uniform within block (n0 64-aligned)
    const int dd = ncol0 & 255;
    #pragma unroll
    for (int i = 0; i < 4; ++i) {
        int m = m0 + ty*4 + i;
        int bb = m >> 11, ss = m & 2047;
        float4 o;
        o.x = acc[i][0] + bv4.x; o.y = acc[i][1] + bv4.y;
        o.z = acc[i][2] + bv4.z; o.w = acc[i][3] + bv4.w;
        *(float4*)&outp[(((size_t)bb*NH + h)*SQ + ss)*DH + dd] = o;
    }
}

// ===================== Kernel B: flash attention (fp32) =====================
// grid: x = S/64 q-tiles (32), y = b*h (32). 256 threads, BQ=BK=64.
// Scores kept in LDS transposed: Pt[key][qrow] (pad 68) -> b128 reads in PV.
__global__ void __launch_bounds__(256) attn_kernel(
    const float* __restrict__ q_ws, const float* __restrict__ k_ws,
    const float* __restrict__ v_ws, const int* __restrict__ mask,
    float* __restrict__ o_ws)
{
    __shared__ float Qt[32*68];   // [kk][qrow]
    __shared__ float Kt[32*68];   // [kk][key]
    __shared__ float Pt[64*68];   // [key][qrow]
    __shared__ float Vs[64*68];   // [key][d-chunk col]
    __shared__ float m_s[64], l_s[64], rfac[64];
    __shared__ float red[64*4];

    const int tid = threadIdx.x;
    const int bh = blockIdx.y;            // b*8+h
    const int q0 = blockIdx.x * 64;
    const float* __restrict__ qp = q_ws + (size_t)bh * SQ * DH;
    const float* __restrict__ kp = k_ws + (size_t)bh * SQ * DH;
    const float* __restrict__ vp = v_ws + (size_t)bh * SQ * DH;
    const int* __restrict__ mp = mask + (bh >> 3) * SQ;

    if (tid < 64) { m_s[tid] = -3.0e38f; l_s[tid] = 0.0f; }

    const int tx = tid & 15, ty = tid >> 4;     // phase-1 map
    const int lrow = tid >> 2, lk0 = (tid & 3) * 8;  // staging map
    const int srow = tid >> 2, spart = tid & 3;      // softmax map
    const int rg = tid >> 4, cg = tid & 15;          // PV map (rows rg*4+i, cols cg*4+j per chunk)

    float acc[4][16] = {};   // [i][dc*4+j] -> output rows rg*4+i, d = dc*64+cg*4+j
    __syncthreads();

    for (int kb = 0; kb < SQ; kb += 64) {
        // ---- Phase 1: scores sc[key j][qrow i] ----
        float sc[4][4] = {};
        for (int kc = 0; kc < 256; kc += 32) {
            float4 qa = *(const float4*)&qp[(size_t)(q0 + lrow)*DH + kc + lk0];
            float4 qb = *(const float4*)&qp[(size_t)(q0 + lrow)*DH + kc + lk0 + 4];
            float4 ka = *(const float4*)&kp[(size_t)(kb + lrow)*DH + kc + lk0];
            float4 kb4= *(const float4*)&kp[(size_t)(kb + lrow)*DH + kc + lk0 + 4];
            __syncthreads();
            Qt[(lk0+0)*68 + lrow] = qa.x; Qt[(lk0+1)*68 + lrow] = qa.y;
            Qt[(lk0+2)*68 + lrow] = qa.z; Qt[(lk0+3)*68 + lrow] = qa.w;
            Qt[(lk0+4)*68 + lrow] = qb.x; Qt[(lk0+5)*68 + lrow] = qb.y;
            Qt[(lk0+6)*68 + lrow] = qb.z; Qt[(lk0+7)*68 + lrow] = qb.w;
            Kt[(lk0+0)*68 + lrow] = ka.x; Kt[(lk0+1)*68 + lrow] = ka.y;
            Kt[(lk0+2)*68 + lrow] = ka.z; Kt[(lk0+3)*68 + lrow] = ka.w;
            Kt[(lk0+4)*68 + lrow] = kb4.x; Kt[(lk0+5)*68 + lrow] = kb4.y;
            Kt[(lk0+6)*68 + lrow] = kb4.z; Kt[(lk0+7)*68 + lrow] = kb4.w;
            __syncthreads();
            #pragma unroll 8
            for (int kk = 0; kk < 32; ++kk) {
                float4 a4 = *(float4*)&Qt[kk*68 + ty*4];
                float4 b4 = *(float4*)&Kt[kk*68 + tx*4];
                float a[4] = {a4.x, a4.y, a4.z, a4.w};
                float b[4] = {b4.x, b4.y, b4.z, b4.w};
                #pragma unroll
                for (int j = 0; j < 4; ++j)
                    #pragma unroll
                    for (int i = 0; i < 4; ++i)
                        sc[j][i] += b[j] * a[i];
            }
        }
        // scale + key-mask + store transposed P[key][qrow]
        int km[4];
        #pragma unroll
        for (int j = 0; j < 4; ++j) km[j] = mp[kb + tx*4 + j];
        #pragma unroll
        for (int j = 0; j < 4; ++j) {
            float4 o;
            o.x = km[j] ? sc[j][0]*0.0625f : -1e9f;
            o.y = km[j] ? sc[j][1]*0.0625f : -1e9f;
            o.z = km[j] ? sc[j][2]*0.0625f : -1e9f;
            o.w = km[j] ? sc[j][3]*0.0625f : -1e9f;
            *(float4*)&Pt[(tx*4 + j)*68 + ty*4] = o;
        }
        __syncthreads();

        // ---- Phase 2: online softmax (4 threads per q-row) ----
        float lm = -3.0e38f;
        #pragma unroll
        for (int c = 0; c < 16; ++c)
            lm = fmaxf(lm, Pt[(spart*16 + c)*68 + srow]);
        red[srow*4 + spart] = lm;
        __syncthreads();
        float m_new = fmaxf(m_s[srow],
                      fmaxf(fmaxf(red[srow*4+0], red[srow*4+1]),
                            fmaxf(red[srow*4+2], red[srow*4+3])));
        float lsum = 0.0f;
        #pragma unroll
        for (int c = 0; c < 16; ++c) {
            int idx = (spart*16 + c)*68 + srow;
            float p = __expf(Pt[idx] - m_new);
            Pt[idx] = p;
            lsum += p;
        }
        __syncthreads();                  // red reuse
        red[srow*4 + spart] = lsum;
        __syncthreads();
        if (spart == 0) {
            float rsum = red[srow*4+0] + red[srow*4+1] + red[srow*4+2] + red[srow*4+3];
            float rf = __expf(m_s[srow] - m_new);
            rfac[srow] = rf;
            l_s[srow] = l_s[srow] * rf + rsum;
            m_s[srow] = m_new;
        }
        __syncthreads();

        // ---- Phase 3: PV, rescale then accumulate ----
        #pragma unroll
        for (int i = 0; i < 4; ++i) {
            float rf = rfac[rg*4 + i];
            #pragma unroll
            for (int c = 0; c < 16; ++c) acc[i][c] *= rf;
        }
        #pragma unroll
        for (int dc = 0; dc < 4; ++dc) {
            __syncthreads();   // previous Vs chunk consumed
            #pragma unroll
            for (int t = 0; t < 16; ++t) {
                int idx = tid + t*256;
                int vr = idx >> 6, vc = idx & 63;
                Vs[vr*68 + vc] = vp[(size_t)(kb + vr)*DH + dc*64 + vc];
            }
            __syncthreads();
            for (int kk = 0; kk < 64; ++kk) {
                float4 p4 = *(float4*)&Pt[kk*68 + rg*4];
                float4 v4 = *(float4*)&Vs[kk*68 + cg*4];
                float p[4] = {p4.x, p4.y, p4.z, p4.w};
                float v[4] = {v4.x, v4.y, v4.z, v4.w};
                #pragma unroll
                for (int i = 0; i < 4; ++i)
                    #pragma unroll
                    for (int j = 0; j < 4; ++j)
                        acc[i][dc*4 + j] += p[i] * v[j];
            }
        }
    }

    // epilogue: normalize by l, write [bh][s][d]
    #pragma unroll
    for (int i = 0; i < 4; ++i) {
        float inv = 1.0f / l_s[rg*4 + i];
        #pragma unroll
        for (int dc = 0; dc < 4; ++dc) {
            float4 o;
            o.x = acc[i][dc*4+0] * inv; o.y = acc[i][dc*4+1] * inv;
            o.z = acc[i][dc*4+2] * inv; o.w = acc[i][dc*4+3] * inv;
            *(float4*)&o_ws[((size_t)bh*SQ + q0 + rg*4 + i)*DH + dc*64 + cg*4] = o;
        }
    }
}

// ============ Kernel C: out-projection + bias + residual + LayerNorm ============
// A (attn out, head-major) viewed as [8192, 2048]; Wo:[256,2048]; out:[8192,256].
// Block: 32 rows x 256 cols; thread owns one column, 32 rows.
__global__ void __launch_bounds__(256) oproj_ln_kernel(
    const float* __restrict__ A, const float* __restrict__ Wo,
    const float* __restrict__ bo, const float* __restrict__ Xin,
    const float* __restrict__ g, const float* __restrict__ be,
    float* __restrict__ out)
{
    __shared__ float As[32*36];      // [kk][row]
    __shared__ float Wsh[256*33];    // [n][kk]
    __shared__ float part1[32*4], part2[32*4];
    const int tid = threadIdx.x;
    const int m0 = blockIdx.x * 32;
    const int c = tid;                       // output column 0..255
    const int arow = tid >> 3, ak0 = (tid & 7) * 4;   // A stage
    const int wn = tid >> 3, wk0 = (tid & 7) * 4;     // W stage

    float acc[32] = {};

    for (int kc = 0; kc < HID; kc += 32) {
        // A chunk [32 rows][32 k], k = h*256+dd in head-major ws
        int m = m0 + arow;
        int bb = m >> 11, ss = m & 2047;
        int h = kc >> 8;
        int dd = (kc & 255) + ak0;
        float4 av = *(const float4*)&A[(((size_t)bb*NH + h)*SQ + ss)*DH + dd];
        float4 wv[8];
        #pragma unroll
        for (int t = 0; t < 8; ++t)
            wv[t] = *(const float4*)&Wo[(size_t)(wn + t*32)*HID + kc + wk0];
        __syncthreads();
        As[(ak0+0)*36 + arow] = av.x; As[(ak0+1)*36 + arow] = av.y;
        As[(ak0+2)*36 + arow] = av.z; As[(ak0+3)*36 + arow] = av.w;
        #pragma unroll
        for (int t = 0; t < 8; ++t) {
            int n = wn + t*32;
            Wsh[n*33 + wk0+0] = wv[t].x; Wsh[n*33 + wk0+1] = wv[t].y;
            Wsh[n*33 + wk0+2] = wv[t].z; Wsh[n*33 + wk0+3] = wv[t].w;
        }
        __syncthreads();
        #pragma unroll 4
        for (int kk = 0; kk < 32; ++kk) {
            float w = Wsh[c*33 + kk];
            #pragma unroll
            for (int r8 = 0; r8 < 8; ++r8) {
                float4 a = *(float4*)&As[kk*36 + r8*4];
                acc[r8*4+0] += a.x * w; acc[r8*4+1] += a.y * w;
                acc[r8*4+2] += a.z * w; acc[r8*4+3] += a.w * w;
            }
        }
    }

    // bias + residual
    float biasc = bo[c];
    #pragma unroll
    for (int r = 0; r < 32; ++r)
        acc[r] += biasc + Xin[(size_t)(m0 + r)*DH + c];

    // per-row mean/var: wave reduce then cross-wave via LDS
    const int lane = tid & 63, wid = tid >> 6;
    #pragma unroll
    for (int r = 0; r < 32; ++r) {
        float s1 = acc[r], s2 = acc[r]*acc[r];
        #pragma unroll
        for (int off = 32; off >= 1; off >>= 1) {
            s1 += __shfl_xor(s1, off, 64);
            s2 += __shfl_xor(s2, off, 64);
        }
        if (lane == 0) { part1[r*4 + wid] = s1; part2[r*4 + wid] = s2; }
    }
    __syncthreads();
    float gc = g[c], bc = be[c];
    #pragma unroll
    for (int r = 0; r < 32; ++r) {
        float s1 = part1[r*4+0]+part1[r*4+1]+part1[r*4+2]+part1[r*4+3];
        float s2 = part2[r*4+0]+part2[r*4+1]+part2[r*4+2]+part2[r*4+3];
        float mean = s1 * (1.0f/256.0f);
        float var  = s2 * (1.0f/256.0f) - mean*mean;
        float rstd = rsqrtf(var + 1e-5f);
        out[(size_t)(m0 + r)*DH + c] = (acc[r] - mean) * rstd * gc + bc;
    }
}

// ===================== launch =====================
extern "C" void kernel_launch(void* const* d_in, const int* in_sizes, int n_in,
                              void* d_out, int out_size, void* d_ws, size_t ws_size,
                              hipStream_t stream) {
    const float* Q    = (const float*)d_in[0];
    const int*   mask = (const int*)  d_in[1];
    const float* WQ_w = (const float*)d_in[2];
    const float* WQ_b = (const float*)d_in[3];
    const float* WK_w = (const float*)d_in[4];
    const float* WK_b = (const float*)d_in[5];
    const float* WV_w = (const float*)d_in[6];
    const float* WV_b = (const float*)d_in[7];
    const float* WO_w = (const float*)d_in[8];
    const float* WO_b = (const float*)d_in[9];
    const float* ln_g = (const float*)d_in[10];
    const float* ln_b = (const float*)d_in[11];
    float* out = (float*)d_out;

    float* ws = (float*)d_ws;
    const size_t NPLANE = (size_t)MROWS * HID;   // 16.8M floats
    float* q_ws = ws;
    float* k_ws = ws + NPLANE;
    float* v_ws = ws + 2*NPLANE;
    float* o_ws = ws + 3*NPLANE;

    qkv_proj_kernel<<<dim3(MROWS/64, (3*HID)/64), 256, 0, stream>>>(
        Q, WQ_w, WK_w, WV_w, WQ_b, WK_b, WV_b, q_ws, k_ws, v_ws);
    attn_kernel<<<dim3(SQ/64, BATCH*NH), 256, 0, stream>>>(
        q_ws, k_ws, v_ws, mask, o_ws);
    oproj_ln_kernel<<<dim3(MROWS/32), 256, 0, stream>>>(
        o_ws, WO_w, WO_b, Q, ln_g, ln_b, out);
}

// Round 2
// 354.752 us; speedup vs baseline: 9.0415x; 9.0415x over previous
//
#include <hip/hip_runtime.h>
#include <cstddef>
#include <cstdint>

#define SQ 2048
#define DH 256
#define NH 8
#define BATCH 4
#define MROWS (BATCH*SQ)   // 8192
#define HID (NH*DH)        // 2048

typedef __attribute__((ext_vector_type(8)))  short bf16x8;
typedef __attribute__((ext_vector_type(16))) float f32x16;

typedef __attribute__((address_space(1))) const unsigned char gbuf_t;
typedef __attribute__((address_space(3))) unsigned char lbuf_t;

__device__ __forceinline__ void gl_lds16(const void* g, void* l) {
  // async global->LDS, 16B per lane; LDS dest is wave-uniform base + lane*16
  __builtin_amdgcn_global_load_lds((gbuf_t*)g, (lbuf_t*)l, 16, 0, 0);
}

__device__ __forceinline__ unsigned short f2bf(float f) {
  unsigned u = __float_as_uint(f);
  unsigned r = (u + 0x7FFFu + ((u >> 16) & 1u)) >> 16;   // RNE
  return (unsigned short)r;
}
__device__ __forceinline__ unsigned pk2(float a, float b) {
  return (unsigned)f2bf(a) | ((unsigned)f2bf(b) << 16);
}
__device__ __forceinline__ f32x16 zero16() {
  f32x16 v;
#pragma unroll
  for (int i = 0; i < 16; ++i) v[i] = 0.0f;
  return v;
}

// ===================== Kernel 0: fp32 -> bf16 conversion =====================
// segments: X 512 chunks, Wq/Wk/Wv/Wo 128 chunks each (chunk = 4096 elems)
__global__ void __launch_bounds__(256) cvt_kernel(
    const float* __restrict__ X,  const float* __restrict__ Wq,
    const float* __restrict__ Wk, const float* __restrict__ Wv,
    const float* __restrict__ Wo,
    unsigned short* __restrict__ Xb,  unsigned short* __restrict__ Wqb,
    unsigned short* __restrict__ Wkb, unsigned short* __restrict__ Wvb,
    unsigned short* __restrict__ Wob)
{
  int bid = blockIdx.x;
  const float* src; unsigned short* dst; size_t off;
  if      (bid < 512) { src = X;  dst = Xb;  off = (size_t)bid * 4096; }
  else if (bid < 640) { src = Wq; dst = Wqb; off = (size_t)(bid - 512) * 4096; }
  else if (bid < 768) { src = Wk; dst = Wkb; off = (size_t)(bid - 640) * 4096; }
  else if (bid < 896) { src = Wv; dst = Wvb; off = (size_t)(bid - 768) * 4096; }
  else                { src = Wo; dst = Wob; off = (size_t)(bid - 896) * 4096; }
  int tid = threadIdx.x;
#pragma unroll
  for (int k = 0; k < 4; ++k) {
    size_t idx = off + ((size_t)k * 256 + tid) * 4;
    float4 v = *(const float4*)(src + idx);
    uint2 o; o.x = pk2(v.x, v.y); o.y = pk2(v.z, v.w);
    *(uint2*)(dst + idx) = o;
  }
}

// ===================== Kernel 1: fused QKV projection (bf16 MFMA) =====================
// z=0: Q = X*Wq^T -> q_ws[bh][s][d];  z=1: K -> k_ws;  z=2: Vt = Wv*X^T -> vt_ws[bh][d][s]
// 128x128 tile, 4 waves (2x2 of 64x64), K=256 one-shot, swizzled global_load_lds staging.
__global__ void __launch_bounds__(256) qkv_kernel(
    const unsigned short* __restrict__ Xbf,
    const unsigned short* __restrict__ Wqb,
    const unsigned short* __restrict__ Wkb,
    const unsigned short* __restrict__ Wvb,
    const float* __restrict__ bq, const float* __restrict__ bk, const float* __restrict__ bv,
    unsigned short* __restrict__ q_ws, unsigned short* __restrict__ k_ws,
    unsigned short* __restrict__ vt_ws)
{
  __shared__ unsigned char TA[65536];   // [128 rows][512B], byte ^= (row&15)<<4
  __shared__ unsigned char TB[65536];
  const int tid = threadIdx.x, w = tid >> 6, l = tid & 63;
  const int h = l >> 5, t = l & 31;
  const int wm = w >> 1, wn = w & 1;
  const int z = blockIdx.z;
  const int m0 = (z == 2) ? blockIdx.y * 128 : blockIdx.x * 128;
  const int n0 = (z == 2) ? blockIdx.x * 128 : blockIdx.y * 128;
  const unsigned short* Asrc = (z == 2) ? Wvb : Xbf;
  const unsigned short* Bsrc = (z == 0) ? Wqb : (z == 1) ? Wkb : Xbf;

  const int rowo = l >> 5;              // 0/1 within 2-row load
  const int bin  = (l & 31) * 16;       // byte-in-row
#pragma unroll
  for (int i2 = 0; i2 < 16; ++i2) {
    int i = 16 * w + i2;
    int row = 2 * i + rowo;
    gl_lds16((const unsigned char*)(Asrc + (size_t)(m0 + row) * 256) + (bin ^ ((row & 15) << 4)),
             &TA[i * 1024]);
  }
#pragma unroll
  for (int i2 = 0; i2 < 16; ++i2) {
    int i = 16 * w + i2;
    int row = 2 * i + rowo;
    gl_lds16((const unsigned char*)(Bsrc + (size_t)(n0 + row) * 256) + (bin ^ ((row & 15) << 4)),
             &TB[i * 1024]);
  }
  __syncthreads();

  f32x16 acc00 = zero16(), acc01 = zero16(), acc10 = zero16(), acc11 = zero16();
  const int swz = (t & 15) << 4;
#pragma unroll
  for (int kc = 0; kc < 16; ++kc) {
    int kb = (32 * kc + 16 * h) ^ swz;
    bf16x8 a0 = *(const bf16x8*)&TA[(size_t)(64 * wm + t) * 512 + kb];
    bf16x8 a1 = *(const bf16x8*)&TA[(size_t)(64 * wm + 32 + t) * 512 + kb];
    bf16x8 b0 = *(const bf16x8*)&TB[(size_t)(64 * wn + t) * 512 + kb];
    bf16x8 b1 = *(const bf16x8*)&TB[(size_t)(64 * wn + 32 + t) * 512 + kb];
    acc00 = __builtin_amdgcn_mfma_f32_32x32x16_bf16(a0, b0, acc00, 0, 0, 0);
    acc01 = __builtin_amdgcn_mfma_f32_32x32x16_bf16(a0, b1, acc01, 0, 0, 0);
    acc10 = __builtin_amdgcn_mfma_f32_32x32x16_bf16(a1, b0, acc10, 0, 0, 0);
    acc11 = __builtin_amdgcn_mfma_f32_32x32x16_bf16(a1, b1, acc11, 0, 0, 0);
  }

  if (z < 2) {
    unsigned short* outp = z ? k_ws : q_ws;
    const float* bias = z ? bk : bq;
    float bn0 = bias[n0 + 64 * wn + t];
    float bn1 = bias[n0 + 64 * wn + 32 + t];
#pragma unroll
    for (int mt = 0; mt < 2; ++mt) {
#pragma unroll
      for (int nt = 0; nt < 2; ++nt) {
        int n = n0 + 64 * wn + 32 * nt + t;
        int headn = n >> 8, d = n & 255;
        float bb = nt ? bn1 : bn0;
        const f32x16& A = (mt == 0) ? (nt == 0 ? acc00 : acc01) : (nt == 0 ? acc10 : acc11);
#pragma unroll
        for (int r = 0; r < 16; ++r) {
          int m = m0 + 64 * wm + 32 * mt + (r & 3) + 8 * (r >> 2) + 4 * h;
          int batch = m >> 11, s = m & 2047;
          outp[(((size_t)batch * NH + headn) * SQ + s) * DH + d] = f2bf(A[r] + bb);
        }
      }
    }
  } else {
#pragma unroll
    for (int mt = 0; mt < 2; ++mt) {
#pragma unroll
      for (int r = 0; r < 16; ++r) {
        int j = m0 + 64 * wm + 32 * mt + (r & 3) + 8 * (r >> 2) + 4 * h;
        float bj = bv[j];
        int headj = j >> 8, jl = j & 255;
#pragma unroll
        for (int nt = 0; nt < 2; ++nt) {
          int sall = n0 + 64 * wn + 32 * nt + t;
          int batch = sall >> 11, ss = sall & 2047;
          const f32x16& A = (mt == 0) ? (nt == 0 ? acc00 : acc01) : (nt == 0 ? acc10 : acc11);
          vt_ws[((size_t)batch * NH + headj) * DH * SQ + (size_t)jl * SQ + ss] = f2bf(A[r] + bj);
        }
      }
    }
  }
}

// ===================== Kernel 2: flash attention (bf16 MFMA, swapped QK^T) =====================
// 4 waves x 32 q-rows (block q-tile 128), KVBLK=64, D=256.
// S^T = mfma(K, Q^T): each lane owns one q-row -> lane-local softmax.
// P->bf16 A-frags via pack + shfl_xor(32). V consumed from transposed vt_ws.
__global__ void __launch_bounds__(256, 2) attn_kernel(
    const unsigned short* __restrict__ q_ws,
    const unsigned short* __restrict__ k_ws,
    const unsigned short* __restrict__ vt_ws,
    const int* __restrict__ mask,
    unsigned short* __restrict__ o_ws)
{
  __shared__ unsigned char KT[32768];   // [64 keys][512B], byte ^= (row&15)<<4
  __shared__ unsigned char VT[32768];   // [256 d][128B],   byte ^= (row&7)<<4
  __shared__ float MB[2048];            // mask bias (0 / -1e9) for this batch

  const int tid = threadIdx.x, w = tid >> 6, l = tid & 63;
  const int h = l >> 5, t = l & 31;
  const int bh = blockIdx.y;
  const int b = bh >> 3, head = bh & 7;
  const int q0 = blockIdx.x * 128;

  {
    const int* mrow = mask + b * SQ;
    for (int i = tid; i < SQ; i += 256) MB[i] = mrow[i] ? 0.0f : -1e9f;
  }

  // Q fragments (B operand: col=q=t, k=d contiguous)
  bf16x8 qf[16];
  {
    const unsigned short* qb = q_ws + ((size_t)bh * SQ + (q0 + 32 * w + t)) * DH + 8 * h;
#pragma unroll
    for (int kc = 0; kc < 16; ++kc) qf[kc] = *(const bf16x8*)(qb + 16 * kc);
  }

  f32x16 o[8];
#pragma unroll
  for (int i = 0; i < 8; ++i) o[i] = zero16();
  float m_run = -3.0e38f, l_run = 0.0f;

  const int swzK = (t & 15) << 4;
  const int swzV = (t & 7) << 4;
  const int krow_off = l >> 5, kb_in = (l & 31) * 16;
  const int vrow_off = l >> 3, vb_in = (l & 7) * 16;
  const unsigned short* kplane = k_ws + (size_t)bh * SQ * DH;
  const unsigned short* vplane = vt_ws + (size_t)bh * DH * SQ;

  for (int kb = 0; kb < SQ; kb += 64) {
    __syncthreads();
    // stage K tile (32KB) + V tile (32KB), pre-swizzled sources
#pragma unroll
    for (int i2 = 0; i2 < 8; ++i2) {
      int i = 8 * w + i2;
      int row = 2 * i + krow_off;
      gl_lds16((const unsigned char*)(kplane + (size_t)(kb + row) * DH) + (kb_in ^ ((row & 15) << 4)),
               &KT[i * 1024]);
    }
#pragma unroll
    for (int i2 = 0; i2 < 8; ++i2) {
      int i = 8 * w + i2;
      int row = 8 * i + vrow_off;          // d-row 0..255
      gl_lds16((const unsigned char*)(vplane + (size_t)row * SQ + kb) + (vb_in ^ ((row & 7) << 4)),
               &VT[i * 1024]);
    }
    __syncthreads();

    // ---- QK^T (swapped): S^T[key][q] ----
    f32x16 sa0 = zero16(), sa1 = zero16();
#pragma unroll
    for (int kc = 0; kc < 16; ++kc) {
      int kbb = (32 * kc + 16 * h) ^ swzK;
      bf16x8 a0 = *(const bf16x8*)&KT[(size_t)t * 512 + kbb];
      bf16x8 a1 = *(const bf16x8*)&KT[(size_t)(32 + t) * 512 + kbb];
      sa0 = __builtin_amdgcn_mfma_f32_32x32x16_bf16(a0, qf[kc], sa0, 0, 0, 0);
      sa1 = __builtin_amdgcn_mfma_f32_32x32x16_bf16(a1, qf[kc], sa1, 0, 0, 0);
    }

    // ---- lane-local online softmax ----
    float tm = -3.0e38f;
    const float* mbp = &MB[kb + 4 * h];
#pragma unroll
    for (int r = 0; r < 16; ++r) {
      int kl = (r & 3) + 8 * (r >> 2);
      sa0[r] = sa0[r] * 0.0625f + mbp[kl];
      sa1[r] = sa1[r] * 0.0625f + mbp[32 + kl];
      tm = fmaxf(tm, fmaxf(sa0[r], sa1[r]));
    }
    tm = fmaxf(tm, __shfl_xor(tm, 32, 64));
    float m_new = fmaxf(m_run, tm);
    float rf = __expf(m_run - m_new);
    m_run = m_new;
    float ls = 0.0f;
#pragma unroll
    for (int r = 0; r < 16; ++r) {
      sa0[r] = __expf(sa0[r] - m_new);
      sa1[r] = __expf(sa1[r] - m_new);
      ls += sa0[r] + sa1[r];
    }
    ls += __shfl_xor(ls, 32, 64);
    l_run = l_run * rf + ls;

    // rescale O by rf of each output row (rows != lane's own q -> bpermute)
#pragma unroll
    for (int r = 0; r < 16; ++r) {
      float rr = __shfl(rf, (r & 3) + 8 * (r >> 2) + 4 * h, 64);
#pragma unroll
      for (int db = 0; db < 8; ++db) o[db][r] *= rr;
    }

    // ---- build PV A-fragments in-register (half-exchange across l^32) ----
    bf16x8 pa[4];
#pragma unroll
    for (int ks = 0; ks < 4; ++ks) {
      const f32x16& P = (ks < 2) ? sa0 : sa1;
      const int base = 8 * (ks & 1);
      unsigned lo0 = pk2(P[base + 0], P[base + 1]);
      unsigned lo1 = pk2(P[base + 2], P[base + 3]);
      unsigned hi0 = pk2(P[base + 4], P[base + 5]);
      unsigned hi1 = pk2(P[base + 6], P[base + 7]);
      unsigned s0 = h ? lo0 : hi0;
      unsigned s1 = h ? lo1 : hi1;
      unsigned x0 = (unsigned)__shfl_xor((int)s0, 32, 64);
      unsigned x1 = (unsigned)__shfl_xor((int)s1, 32, 64);
      union { unsigned u[4]; bf16x8 v; } pu;
      pu.u[0] = h ? x0 : lo0;
      pu.u[1] = h ? x1 : lo1;
      pu.u[2] = h ? hi0 : x0;
      pu.u[3] = h ? hi1 : x1;
      pa[ks] = pu.v;
    }

    // ---- PV: O[q][d] += P * V ----
#pragma unroll
    for (int db = 0; db < 8; ++db) {
#pragma unroll
      for (int ks = 0; ks < 4; ++ks) {
        bf16x8 bv = *(const bf16x8*)&VT[(size_t)(32 * db + t) * 128 + ((32 * ks + 16 * h) ^ swzV)];
        o[db] = __builtin_amdgcn_mfma_f32_32x32x16_bf16(pa[ks], bv, o[db], 0, 0, 0);
      }
    }
  }

  // epilogue: normalize, write bf16 [8192][2048] (row = b*2048+s, col = head*256+d)
  float linv = 1.0f / l_run;
  unsigned short* ob = o_ws + (size_t)b * SQ * HID + (size_t)head * DH;
#pragma unroll
  for (int r = 0; r < 16; ++r) {
    int rowr = (r & 3) + 8 * (r >> 2) + 4 * h;
    float li = __shfl(linv, rowr, 64);
    int s = q0 + 32 * w + rowr;
    unsigned short* orow = ob + (size_t)s * HID;
#pragma unroll
    for (int db = 0; db < 8; ++db)
      orow[32 * db + t] = f2bf(o[db][r] * li);
  }
}

// ===================== Kernel 3: out-projection (bf16 MFMA) -> fp32 tmp =====================
// A = o_ws [8192][2048] bf16, B = Wob [256][2048] bf16 -> tmp = A*Wo^T [8192][256] fp32
__global__ void __launch_bounds__(256) oproj_kernel(
    const unsigned short* __restrict__ Abf,
    const unsigned short* __restrict__ Wob,
    float* __restrict__ tmp)
{
  __shared__ unsigned char TA[8192];    // [64 m][128B], byte ^= (row&7)<<4
  __shared__ unsigned char TB[16384];   // [128 n][128B]
  const int tid = threadIdx.x, w = tid >> 6, l = tid & 63;
  const int h = l >> 5, t = l & 31;
  const int wm = w >> 1, wn = w & 1;
  const int m0 = blockIdx.x * 64, n0 = blockIdx.y * 128;
  const int arow_o = l >> 3, ab_in = (l & 7) * 16;
  const int swz = (t & 7) << 4;

  f32x16 acc0 = zero16(), acc1 = zero16();
  for (int chunk = 0; chunk < 32; ++chunk) {
    __syncthreads();
#pragma unroll
    for (int i2 = 0; i2 < 2; ++i2) {
      int i = 2 * w + i2;
      int row = 8 * i + arow_o;
      gl_lds16((const unsigned char*)(Abf + (size_t)(m0 + row) * HID + chunk * 64) + (ab_in ^ ((row & 7) << 4)),
               &TA[i * 1024]);
    }
#pragma unroll
    for (int i2 = 0; i2 < 4; ++i2) {
      int i = 4 * w + i2;
      int row = 8 * i + arow_o;
      gl_lds16((const unsigned char*)(Wob + (size_t)(n0 + row) * HID + chunk * 64) + (ab_in ^ ((row & 7) << 4)),
               &TB[i * 1024]);
    }
    __syncthreads();
#pragma unroll
    for (int kc = 0; kc < 4; ++kc) {
      int kbb = (32 * kc + 16 * h) ^ swz;
      bf16x8 a  = *(const bf16x8*)&TA[(size_t)(32 * wm + t) * 128 + kbb];
      bf16x8 b0 = *(const bf16x8*)&TB[(size_t)(64 * wn + t) * 128 + kbb];
      bf16x8 b1 = *(const bf16x8*)&TB[(size_t)(64 * wn + 32 + t) * 128 + kbb];
      acc0 = __builtin_amdgcn_mfma_f32_32x32x16_bf16(a, b0, acc0, 0, 0, 0);
      acc1 = __builtin_amdgcn_mfma_f32_32x32x16_bf16(a, b1, acc1, 0, 0, 0);
    }
  }
#pragma unroll
  for (int nt = 0; nt < 2; ++nt) {
    const f32x16& A = nt ? acc1 : acc0;
    int n = n0 + 64 * wn + 32 * nt + t;
#pragma unroll
    for (int r = 0; r < 16; ++r) {
      int m = m0 + 32 * wm + (r & 3) + 8 * (r >> 2) + 4 * h;
      tmp[(size_t)m * DH + n] = A[r];
    }
  }
}

// ===================== Kernel 4: bias + residual + LayerNorm (fp32) =====================
__global__ void __launch_bounds__(256) ln_kernel(
    const float* __restrict__ tmp, const float* __restrict__ bo,
    const float* __restrict__ Xin, const float* __restrict__ g,
    const float* __restrict__ be, float* __restrict__ out)
{
  const int tid = threadIdx.x, w = tid >> 6, lane = tid & 63;
  const int row = blockIdx.x * 4 + w;
  float4 v  = ((const float4*)(tmp + (size_t)row * DH))[lane];
  float4 qv = ((const float4*)(Xin + (size_t)row * DH))[lane];
  float4 bb = ((const float4*)bo)[lane];
  v.x += qv.x + bb.x; v.y += qv.y + bb.y; v.z += qv.z + bb.z; v.w += qv.w + bb.w;
  float s1 = v.x + v.y + v.z + v.w;
  float s2 = v.x * v.x + v.y * v.y + v.z * v.z + v.w * v.w;
#pragma unroll
  for (int off = 1; off < 64; off <<= 1) {
    s1 += __shfl_xor(s1, off, 64);
    s2 += __shfl_xor(s2, off, 64);
  }
  float mean = s1 * (1.0f / 256.0f);
  float var = s2 * (1.0f / 256.0f) - mean * mean;
  float rstd = rsqrtf(var + 1e-5f);
  float4 gg = ((const float4*)g)[lane];
  float4 b2 = ((const float4*)be)[lane];
  float4 o;
  o.x = (v.x - mean) * rstd * gg.x + b2.x;
  o.y = (v.y - mean) * rstd * gg.y + b2.y;
  o.z = (v.z - mean) * rstd * gg.z + b2.z;
  o.w = (v.w - mean) * rstd * gg.w + b2.w;
  ((float4*)(out + (size_t)row * DH))[lane] = o;
}

// ===================== launch =====================
extern "C" void kernel_launch(void* const* d_in, const int* in_sizes, int n_in,
                              void* d_out, int out_size, void* d_ws, size_t ws_size,
                              hipStream_t stream) {
  const float* Q    = (const float*)d_in[0];
  const int*   mask = (const int*)  d_in[1];
  const float* WQ_w = (const float*)d_in[2];
  const float* WQ_b = (const float*)d_in[3];
  const float* WK_w = (const float*)d_in[4];
  const float* WK_b = (const float*)d_in[5];
  const float* WV_w = (const float*)d_in[6];
  const float* WV_b = (const float*)d_in[7];
  const float* WO_w = (const float*)d_in[8];
  const float* WO_b = (const float*)d_in[9];
  const float* ln_g = (const float*)d_in[10];
  const float* ln_b = (const float*)d_in[11];
  float* out = (float*)d_out;

  uint8_t* ws = (uint8_t*)d_ws;
  const size_t MB1 = 1048576;
  unsigned short* Xb   = (unsigned short*)(ws + 0 * MB1);    // 4 MB
  unsigned short* Wqb  = (unsigned short*)(ws + 4 * MB1);    // 1 MB
  unsigned short* Wkb  = (unsigned short*)(ws + 5 * MB1);
  unsigned short* Wvb  = (unsigned short*)(ws + 6 * MB1);
  unsigned short* Wob  = (unsigned short*)(ws + 7 * MB1);
  unsigned short* q_ws = (unsigned short*)(ws + 8 * MB1);    // 32 MB
  unsigned short* k_ws = (unsigned short*)(ws + 40 * MB1);   // 32 MB
  unsigned short* vtws = (unsigned short*)(ws + 72 * MB1);   // 32 MB
  unsigned short* o_ws = (unsigned short*)(ws + 104 * MB1);  // 32 MB
  float*          tmpf = (float*)         (ws + 136 * MB1);  // 8 MB

  cvt_kernel<<<1024, 256, 0, stream>>>(Q, WQ_w, WK_w, WV_w, WO_w, Xb, Wqb, Wkb, Wvb, Wob);
  qkv_kernel<<<dim3(64, 16, 3), 256, 0, stream>>>(Xb, Wqb, Wkb, Wvb, WQ_b, WK_b, WV_b,
                                                  q_ws, k_ws, vtws);
  attn_kernel<<<dim3(16, 32), 256, 0, stream>>>(q_ws, k_ws, vtws, mask, o_ws);
  oproj_kernel<<<dim3(128, 2), 256, 0, stream>>>(o_ws, Wob, tmpf);
  ln_kernel<<<2048, 256, 0, stream>>>(tmpf, WO_b, Q, ln_g, ln_b, out);
}

// Round 3
// 312.025 us; speedup vs baseline: 10.2795x; 1.1369x over previous
//
#include <hip/hip_runtime.h>
#include <cstddef>
#include <cstdint>

#define SQ 2048
#define DH 256
#define NH 8
#define BATCH 4
#define MROWS (BATCH*SQ)   // 8192
#define HID (NH*DH)        // 2048

typedef __attribute__((ext_vector_type(8)))  short bf16x8;
typedef __attribute__((ext_vector_type(16))) float f32x16;

typedef __attribute__((address_space(1))) const unsigned char gbuf_t;
typedef __attribute__((address_space(3))) unsigned char lbuf_t;

__device__ __forceinline__ void gl_lds16(const void* g, void* l) {
  // async global->LDS, 16B per lane; LDS dest is wave-uniform base + lane*16
  __builtin_amdgcn_global_load_lds((gbuf_t*)g, (lbuf_t*)l, 16, 0, 0);
}

__device__ __forceinline__ unsigned short f2bf(float f) {
  unsigned u = __float_as_uint(f);
  unsigned r = (u + 0x7FFFu + ((u >> 16) & 1u)) >> 16;   // RNE
  return (unsigned short)r;
}
__device__ __forceinline__ unsigned pk2(float a, float b) {
  return (unsigned)f2bf(a) | ((unsigned)f2bf(b) << 16);
}
__device__ __forceinline__ f32x16 zero16() {
  f32x16 v;
#pragma unroll
  for (int i = 0; i < 16; ++i) v[i] = 0.0f;
  return v;
}

// ===================== Kernel 0: fp32 -> bf16 conversion =====================
__global__ void __launch_bounds__(256) cvt_kernel(
    const float* __restrict__ X,  const float* __restrict__ Wq,
    const float* __restrict__ Wk, const float* __restrict__ Wv,
    const float* __restrict__ Wo,
    unsigned short* __restrict__ Xb,  unsigned short* __restrict__ Wqb,
    unsigned short* __restrict__ Wkb, unsigned short* __restrict__ Wvb,
    unsigned short* __restrict__ Wob)
{
  int bid = blockIdx.x;
  const float* src; unsigned short* dst; size_t off;
  if      (bid < 512) { src = X;  dst = Xb;  off = (size_t)bid * 4096; }
  else if (bid < 640) { src = Wq; dst = Wqb; off = (size_t)(bid - 512) * 4096; }
  else if (bid < 768) { src = Wk; dst = Wkb; off = (size_t)(bid - 640) * 4096; }
  else if (bid < 896) { src = Wv; dst = Wvb; off = (size_t)(bid - 768) * 4096; }
  else                { src = Wo; dst = Wob; off = (size_t)(bid - 896) * 4096; }
  int tid = threadIdx.x;
#pragma unroll
  for (int k = 0; k < 4; ++k) {
    size_t idx = off + ((size_t)k * 256 + tid) * 4;
    float4 v = *(const float4*)(src + idx);
    uint2 o; o.x = pk2(v.x, v.y); o.y = pk2(v.z, v.w);
    *(uint2*)(dst + idx) = o;
  }
}

// ===================== Kernel 1: fused QKV projection (bf16 MFMA) =====================
__global__ void __launch_bounds__(256) qkv_kernel(
    const unsigned short* __restrict__ Xbf,
    const unsigned short* __restrict__ Wqb,
    const unsigned short* __restrict__ Wkb,
    const unsigned short* __restrict__ Wvb,
    const float* __restrict__ bq, const float* __restrict__ bk, const float* __restrict__ bv,
    unsigned short* __restrict__ q_ws, unsigned short* __restrict__ k_ws,
    unsigned short* __restrict__ vt_ws)
{
  __shared__ unsigned char TA[65536];   // [128 rows][512B], byte ^= (row&15)<<4
  __shared__ unsigned char TB[65536];
  const int tid = threadIdx.x, w = tid >> 6, l = tid & 63;
  const int h = l >> 5, t = l & 31;
  const int wm = w >> 1, wn = w & 1;
  const int z = blockIdx.z;
  const int m0 = (z == 2) ? blockIdx.y * 128 : blockIdx.x * 128;
  const int n0 = (z == 2) ? blockIdx.x * 128 : blockIdx.y * 128;
  const unsigned short* Asrc = (z == 2) ? Wvb : Xbf;
  const unsigned short* Bsrc = (z == 0) ? Wqb : (z == 1) ? Wkb : Xbf;

  const int rowo = l >> 5;
  const int bin  = (l & 31) * 16;
#pragma unroll
  for (int i2 = 0; i2 < 16; ++i2) {
    int i = 16 * w + i2;
    int row = 2 * i + rowo;
    gl_lds16((const unsigned char*)(Asrc + (size_t)(m0 + row) * 256) + (bin ^ ((row & 15) << 4)),
             &TA[i * 1024]);
  }
#pragma unroll
  for (int i2 = 0; i2 < 16; ++i2) {
    int i = 16 * w + i2;
    int row = 2 * i + rowo;
    gl_lds16((const unsigned char*)(Bsrc + (size_t)(n0 + row) * 256) + (bin ^ ((row & 15) << 4)),
             &TB[i * 1024]);
  }
  __syncthreads();

  f32x16 acc00 = zero16(), acc01 = zero16(), acc10 = zero16(), acc11 = zero16();
  const int swz = (t & 15) << 4;
#pragma unroll
  for (int kc = 0; kc < 16; ++kc) {
    int kb = (32 * kc + 16 * h) ^ swz;
    bf16x8 a0 = *(const bf16x8*)&TA[(size_t)(64 * wm + t) * 512 + kb];
    bf16x8 a1 = *(const bf16x8*)&TA[(size_t)(64 * wm + 32 + t) * 512 + kb];
    bf16x8 b0 = *(const bf16x8*)&TB[(size_t)(64 * wn + t) * 512 + kb];
    bf16x8 b1 = *(const bf16x8*)&TB[(size_t)(64 * wn + 32 + t) * 512 + kb];
    acc00 = __builtin_amdgcn_mfma_f32_32x32x16_bf16(a0, b0, acc00, 0, 0, 0);
    acc01 = __builtin_amdgcn_mfma_f32_32x32x16_bf16(a0, b1, acc01, 0, 0, 0);
    acc10 = __builtin_amdgcn_mfma_f32_32x32x16_bf16(a1, b0, acc10, 0, 0, 0);
    acc11 = __builtin_amdgcn_mfma_f32_32x32x16_bf16(a1, b1, acc11, 0, 0, 0);
  }

  if (z < 2) {
    unsigned short* outp = z ? k_ws : q_ws;
    const float* bias = z ? bk : bq;
    float bn0 = bias[n0 + 64 * wn + t];
    float bn1 = bias[n0 + 64 * wn + 32 + t];
#pragma unroll
    for (int mt = 0; mt < 2; ++mt) {
#pragma unroll
      for (int nt = 0; nt < 2; ++nt) {
        int n = n0 + 64 * wn + 32 * nt + t;
        int headn = n >> 8, d = n & 255;
        float bb = nt ? bn1 : bn0;
        const f32x16& A = (mt == 0) ? (nt == 0 ? acc00 : acc01) : (nt == 0 ? acc10 : acc11);
#pragma unroll
        for (int r = 0; r < 16; ++r) {
          int m = m0 + 64 * wm + 32 * mt + (r & 3) + 8 * (r >> 2) + 4 * h;
          int batch = m >> 11, s = m & 2047;
          outp[(((size_t)batch * NH + headn) * SQ + s) * DH + d] = f2bf(A[r] + bb);
        }
      }
    }
  } else {
#pragma unroll
    for (int mt = 0; mt < 2; ++mt) {
#pragma unroll
      for (int r = 0; r < 16; ++r) {
        int j = m0 + 64 * wm + 32 * mt + (r & 3) + 8 * (r >> 2) + 4 * h;
        float bj = bv[j];
        int headj = j >> 8, jl = j & 255;
#pragma unroll
        for (int nt = 0; nt < 2; ++nt) {
          int sall = n0 + 64 * wn + 32 * nt + t;
          int batch = sall >> 11, ss = sall & 2047;
          const f32x16& A = (mt == 0) ? (nt == 0 ? acc00 : acc01) : (nt == 0 ? acc10 : acc11);
          vt_ws[((size_t)batch * NH + headj) * DH * SQ + (size_t)jl * SQ + ss] = f2bf(A[r] + bj);
        }
      }
    }
  }
}

// ===================== Kernel 2: flash attention — 8-wave, 2-phase pipelined =====================
// 8 waves x 32 q-rows (q-tile 256), KVBLK=64, double-buffered K and V tiles,
// ONE barrier per tile, prefetch t+1 issued before compute of t, setprio on MFMA.
// Grid = 256 blocks (1/CU), bijective XCD swizzle so all 8 q-tiles of a bh share an XCD.
__global__ void __launch_bounds__(512, 2) attn_kernel(
    const unsigned short* __restrict__ q_ws,
    const unsigned short* __restrict__ k_ws,
    const unsigned short* __restrict__ vt_ws,
    const int* __restrict__ mask,
    unsigned short* __restrict__ o_ws)
{
  __shared__ unsigned char KT[2][32768];  // [64 keys][512B], byte ^= (row&15)<<4
  __shared__ unsigned char VT[2][32768];  // [256 d][128B],   byte ^= (row&7)<<4
  __shared__ float MB[2048];              // mask bias for this batch

  const int tid = threadIdx.x, w = tid >> 6, l = tid & 63;
  const int h = l >> 5, t = l & 31;
  // XCD-aware decode: bid%8 = XCD; give each XCD 4 bh x 8 q-tiles
  const int bid = blockIdx.x;
  const int xcd = bid & 7, slot = bid >> 3;
  const int bh = xcd * 4 + (slot >> 3);
  const int qt = slot & 7;
  const int b = bh >> 3, head = bh & 7;
  const int q0 = qt * 256;

  {
    const int* mrow = mask + b * SQ;
    for (int i = tid; i < SQ; i += 512) MB[i] = mrow[i] ? 0.0f : -1e9f;
  }

  const unsigned short* kplane = k_ws + (size_t)bh * SQ * DH;
  const unsigned short* vplane = vt_ws + (size_t)bh * DH * SQ;

  // Q fragments (B operand: col=q=t, k=d contiguous)
  bf16x8 qf[16];
  {
    const unsigned short* qb = q_ws + ((size_t)bh * SQ + (q0 + 32 * w + t)) * DH + 8 * h;
#pragma unroll
    for (int kc = 0; kc < 16; ++kc) qf[kc] = *(const bf16x8*)(qb + 16 * kc);
  }

  const int krow_o = l >> 5, kcol = (l & 31) * 16;
  const int vrow_o = l >> 3, vcol = (l & 7) * 16;

  // prologue: stage tile 0 into buf 0
  {
#pragma unroll
    for (int i = 0; i < 4; ++i) {
      int j = 4 * w + i;
      int row = 2 * j + krow_o;
      gl_lds16((const unsigned char*)(kplane + (size_t)row * DH) + (kcol ^ ((row & 15) << 4)),
               &KT[0][j * 1024]);
    }
#pragma unroll
    for (int i = 0; i < 4; ++i) {
      int j = 4 * w + i;
      int row = 8 * j + vrow_o;
      gl_lds16((const unsigned char*)(vplane + (size_t)row * SQ) + (vcol ^ ((row & 7) << 4)),
               &VT[0][j * 1024]);
    }
  }
  __syncthreads();   // drains vmcnt -> tile 0 resident

  f32x16 o[8];
#pragma unroll
  for (int i = 0; i < 8; ++i) o[i] = zero16();
  float m_run = -3.0e38f, l_run = 0.0f;

  const int swzK = (t & 15) << 4;
  const int swzV = (t & 7) << 4;

  int cur = 0;
  for (int kb = 0; kb < SQ; kb += 64) {
    const int nxt = cur ^ 1;
    // ---- issue prefetch of tile t+1 (lands at end-of-tile barrier) ----
    if (kb + 64 < SQ) {
#pragma unroll
      for (int i = 0; i < 4; ++i) {
        int j = 4 * w + i;
        int row = 2 * j + krow_o;
        gl_lds16((const unsigned char*)(kplane + (size_t)(kb + 64 + row) * DH) + (kcol ^ ((row & 15) << 4)),
                 &KT[nxt][j * 1024]);
      }
#pragma unroll
      for (int i = 0; i < 4; ++i) {
        int j = 4 * w + i;
        int row = 8 * j + vrow_o;
        gl_lds16((const unsigned char*)(vplane + (size_t)row * SQ + kb + 64) + (vcol ^ ((row & 7) << 4)),
                 &VT[nxt][j * 1024]);
      }
    }

    // ---- QK^T (swapped): S^T[key][q] ----
    f32x16 sa0 = zero16(), sa1 = zero16();
    __builtin_amdgcn_s_setprio(1);
#pragma unroll
    for (int kc = 0; kc < 16; ++kc) {
      int kbb = (32 * kc + 16 * h) ^ swzK;
      bf16x8 a0 = *(const bf16x8*)&KT[cur][(size_t)t * 512 + kbb];
      bf16x8 a1 = *(const bf16x8*)&KT[cur][(size_t)(32 + t) * 512 + kbb];
      sa0 = __builtin_amdgcn_mfma_f32_32x32x16_bf16(a0, qf[kc], sa0, 0, 0, 0);
      sa1 = __builtin_amdgcn_mfma_f32_32x32x16_bf16(a1, qf[kc], sa1, 0, 0, 0);
    }
    __builtin_amdgcn_s_setprio(0);

    // ---- lane-local online softmax ----
    float tm = -3.0e38f;
    const float* mbp = &MB[kb + 4 * h];
#pragma unroll
    for (int r = 0; r < 16; ++r) {
      int kl = (r & 3) + 8 * (r >> 2);
      sa0[r] = sa0[r] * 0.0625f + mbp[kl];
      sa1[r] = sa1[r] * 0.0625f + mbp[32 + kl];
      tm = fmaxf(tm, fmaxf(sa0[r], sa1[r]));
    }
    tm = fmaxf(tm, __shfl_xor(tm, 32, 64));
    float m_new = fmaxf(m_run, tm);
    float rf = __expf(m_run - m_new);
    m_run = m_new;
    float ls = 0.0f;
#pragma unroll
    for (int r = 0; r < 16; ++r) {
      sa0[r] = __expf(sa0[r] - m_new);
      sa1[r] = __expf(sa1[r] - m_new);
      ls += sa0[r] + sa1[r];
    }
    ls += __shfl_xor(ls, 32, 64);
    l_run = l_run * rf + ls;

    // rescale O by each output row's rf
#pragma unroll
    for (int r = 0; r < 16; ++r) {
      float rr = __shfl(rf, (r & 3) + 8 * (r >> 2) + 4 * h, 64);
#pragma unroll
      for (int db = 0; db < 8; ++db) o[db][r] *= rr;
    }

    // ---- build PV A-fragments in-register (half-exchange across l^32) ----
    bf16x8 pa[4];
#pragma unroll
    for (int ks = 0; ks < 4; ++ks) {
      const f32x16& P = (ks < 2) ? sa0 : sa1;
      const int base = 8 * (ks & 1);
      unsigned lo0 = pk2(P[base + 0], P[base + 1]);
      unsigned lo1 = pk2(P[base + 2], P[base + 3]);
      unsigned hi0 = pk2(P[base + 4], P[base + 5]);
      unsigned hi1 = pk2(P[base + 6], P[base + 7]);
      unsigned s0 = h ? lo0 : hi0;
      unsigned s1 = h ? lo1 : hi1;
      unsigned x0 = (unsigned)__shfl_xor((int)s0, 32, 64);
      unsigned x1 = (unsigned)__shfl_xor((int)s1, 32, 64);
      union { unsigned u[4]; bf16x8 v; } pu;
      pu.u[0] = h ? x0 : lo0;
      pu.u[1] = h ? x1 : lo1;
      pu.u[2] = h ? hi0 : x0;
      pu.u[3] = h ? hi1 : x1;
      pa[ks] = pu.v;
    }

    // ---- PV: O[q][d] += P * V ----
    __builtin_amdgcn_s_setprio(1);
#pragma unroll
    for (int db = 0; db < 8; ++db) {
#pragma unroll
      for (int ks = 0; ks < 4; ++ks) {
        bf16x8 bv = *(const bf16x8*)&VT[cur][(size_t)(32 * db + t) * 128 + ((32 * ks + 16 * h) ^ swzV)];
        o[db] = __builtin_amdgcn_mfma_f32_32x32x16_bf16(pa[ks], bv, o[db], 0, 0, 0);
      }
    }
    __builtin_amdgcn_s_setprio(0);

    __syncthreads();   // drains prefetch vmcnt; tile t+1 resident in [nxt]
    cur = nxt;
  }

  // epilogue: normalize, write bf16 [8192][2048] (row = b*2048+s, col = head*256+d)
  float linv = 1.0f / l_run;
  unsigned short* ob = o_ws + (size_t)b * SQ * HID + (size_t)head * DH;
#pragma unroll
  for (int r = 0; r < 16; ++r) {
    int rowr = (r & 3) + 8 * (r >> 2) + 4 * h;
    float li = __shfl(linv, rowr, 64);
    int s = q0 + 32 * w + rowr;
    unsigned short* orow = ob + (size_t)s * HID;
#pragma unroll
    for (int db = 0; db < 8; ++db)
      orow[32 * db + t] = f2bf(o[db][r] * li);
  }
}

// ===================== Kernel 3: out-projection (bf16 MFMA) -> fp32 tmp =====================
__global__ void __launch_bounds__(256) oproj_kernel(
    const unsigned short* __restrict__ Abf,
    const unsigned short* __restrict__ Wob,
    float* __restrict__ tmp)
{
  __shared__ unsigned char TA[8192];    // [64 m][128B], byte ^= (row&7)<<4
  __shared__ unsigned char TB[16384];   // [128 n][128B]
  const int tid = threadIdx.x, w = tid >> 6, l = tid & 63;
  const int h = l >> 5, t = l & 31;
  const int wm = w >> 1, wn = w & 1;
  const int m0 = blockIdx.x * 64, n0 = blockIdx.y * 128;
  const int arow_o = l >> 3, ab_in = (l & 7) * 16;
  const int swz = (t & 7) << 4;

  f32x16 acc0 = zero16(), acc1 = zero16();
  for (int chunk = 0; chunk < 32; ++chunk) {
    __syncthreads();
#pragma unroll
    for (int i2 = 0; i2 < 2; ++i2) {
      int i = 2 * w + i2;
      int row = 8 * i + arow_o;
      gl_lds16((const unsigned char*)(Abf + (size_t)(m0 + row) * HID + chunk * 64) + (ab_in ^ ((row & 7) << 4)),
               &TA[i * 1024]);
    }
#pragma unroll
    for (int i2 = 0; i2 < 4; ++i2) {
      int i = 4 * w + i2;
      int row = 8 * i + arow_o;
      gl_lds16((const unsigned char*)(Wob + (size_t)(n0 + row) * HID + chunk * 64) + (ab_in ^ ((row & 7) << 4)),
               &TB[i * 1024]);
    }
    __syncthreads();
#pragma unroll
    for (int kc = 0; kc < 4; ++kc) {
      int kbb = (32 * kc + 16 * h) ^ swz;
      bf16x8 a  = *(const bf16x8*)&TA[(size_t)(32 * wm + t) * 128 + kbb];
      bf16x8 b0 = *(const bf16x8*)&TB[(size_t)(64 * wn + t) * 128 + kbb];
      bf16x8 b1 = *(const bf16x8*)&TB[(size_t)(64 * wn + 32 + t) * 128 + kbb];
      acc0 = __builtin_amdgcn_mfma_f32_32x32x16_bf16(a, b0, acc0, 0, 0, 0);
      acc1 = __builtin_amdgcn_mfma_f32_32x32x16_bf16(a, b1, acc1, 0, 0, 0);
    }
  }
#pragma unroll
  for (int nt = 0; nt < 2; ++nt) {
    const f32x16& A = nt ? acc1 : acc0;
    int n = n0 + 64 * wn + 32 * nt + t;
#pragma unroll
    for (int r = 0; r < 16; ++r) {
      int m = m0 + 32 * wm + (r & 3) + 8 * (r >> 2) + 4 * h;
      tmp[(size_t)m * DH + n] = A[r];
    }
  }
}

// ===================== Kernel 4: bias + residual + LayerNorm (fp32) =====================
__global__ void __launch_bounds__(256) ln_kernel(
    const float* __restrict__ tmp, const float* __restrict__ bo,
    const float* __restrict__ Xin, const float* __restrict__ g,
    const float* __restrict__ be, float* __restrict__ out)
{
  const int tid = threadIdx.x, w = tid >> 6, lane = tid & 63;
  const int row = blockIdx.x * 4 + w;
  float4 v  = ((const float4*)(tmp + (size_t)row * DH))[lane];
  float4 qv = ((const float4*)(Xin + (size_t)row * DH))[lane];
  float4 bb = ((const float4*)bo)[lane];
  v.x += qv.x + bb.x; v.y += qv.y + bb.y; v.z += qv.z + bb.z; v.w += qv.w + bb.w;
  float s1 = v.x + v.y + v.z + v.w;
  float s2 = v.x * v.x + v.y * v.y + v.z * v.z + v.w * v.w;
#pragma unroll
  for (int off = 1; off < 64; off <<= 1) {
    s1 += __shfl_xor(s1, off, 64);
    s2 += __shfl_xor(s2, off, 64);
  }
  float mean = s1 * (1.0f / 256.0f);
  float var = s2 * (1.0f / 256.0f) - mean * mean;
  float rstd = rsqrtf(var + 1e-5f);
  float4 gg = ((const float4*)g)[lane];
  float4 b2 = ((const float4*)be)[lane];
  float4 o;
  o.x = (v.x - mean) * rstd * gg.x + b2.x;
  o.y = (v.y - mean) * rstd * gg.y + b2.y;
  o.z = (v.z - mean) * rstd * gg.z + b2.z;
  o.w = (v.w - mean) * rstd * gg.w + b2.w;
  ((float4*)(out + (size_t)row * DH))[lane] = o;
}

// ===================== launch =====================
extern "C" void kernel_launch(void* const* d_in, const int* in_sizes, int n_in,
                              void* d_out, int out_size, void* d_ws, size_t ws_size,
                              hipStream_t stream) {
  const float* Q    = (const float*)d_in[0];
  const int*   mask = (const int*)  d_in[1];
  const float* WQ_w = (const float*)d_in[2];
  const float* WQ_b = (const float*)d_in[3];
  const float* WK_w = (const float*)d_in[4];
  const float* WK_b = (const float*)d_in[5];
  const float* WV_w = (const float*)d_in[6];
  const float* WV_b = (const float*)d_in[7];
  const float* WO_w = (const float*)d_in[8];
  const float* WO_b = (const float*)d_in[9];
  const float* ln_g = (const float*)d_in[10];
  const float* ln_b = (const float*)d_in[11];
  float* out = (float*)d_out;

  uint8_t* ws = (uint8_t*)d_ws;
  const size_t MB1 = 1048576;
  unsigned short* Xb   = (unsigned short*)(ws + 0 * MB1);    // 4 MB
  unsigned short* Wqb  = (unsigned short*)(ws + 4 * MB1);    // 1 MB
  unsigned short* Wkb  = (unsigned short*)(ws + 5 * MB1);
  unsigned short* Wvb  = (unsigned short*)(ws + 6 * MB1);
  unsigned short* Wob  = (unsigned short*)(ws + 7 * MB1);
  unsigned short* q_ws = (unsigned short*)(ws + 8 * MB1);    // 32 MB
  unsigned short* k_ws = (unsigned short*)(ws + 40 * MB1);   // 32 MB
  unsigned short* vtws = (unsigned short*)(ws + 72 * MB1);   // 32 MB
  unsigned short* o_ws = (unsigned short*)(ws + 104 * MB1);  // 32 MB
  float*          tmpf = (float*)         (ws + 136 * MB1);  // 8 MB

  cvt_kernel<<<1024, 256, 0, stream>>>(Q, WQ_w, WK_w, WV_w, WO_w, Xb, Wqb, Wkb, Wvb, Wob);
  qkv_kernel<<<dim3(64, 16, 3), 256, 0, stream>>>(Xb, Wqb, Wkb, Wvb, WQ_b, WK_b, WV_b,
                                                  q_ws, k_ws, vtws);
  attn_kernel<<<dim3(256), 512, 0, stream>>>(q_ws, k_ws, vtws, mask, o_ws);
  oproj_kernel<<<dim3(128, 2), 256, 0, stream>>>(o_ws, Wob, tmpf);
  ln_kernel<<<2048, 256, 0, stream>>>(tmpf, WO_b, Q, ln_g, ln_b, out);
}